// Round 13
// baseline (490.344 us; speedup 1.0000x reference)
//
#include <hip/hip_runtime.h>
#include <math.h>

#define BB 2
#define SS 4096
#define HIDK 512
#define HH 8
#define DD 64
#define NHH 4
#define NCC 256      // chunks per (b,h) = NH*S/CHUNK
#define RANKS 16384  // NH*S

typedef unsigned int u32;
typedef unsigned char u8;
typedef __attribute__((ext_vector_type(8))) short bf16x8;
typedef __attribute__((ext_vector_type(4))) float f32x4;

__device__ __forceinline__ float bflo(u32 u){ return __uint_as_float(u << 16); }
__device__ __forceinline__ float bfhi(u32 u){ return __uint_as_float(u & 0xffff0000u); }

// RN fp32 -> bf16 (top of x)
__device__ __forceinline__ unsigned short brn(float x)
{
  u32 u = __float_as_uint(x);
  u32 r = u + 0x7FFFu + ((u >> 16) & 1u);
  return (unsigned short)(r >> 16);
}

// 2-term bf16 split: x ~= b0 + b1 (residual ~2^-17 |x|).
__device__ __forceinline__ void bsplit2(float x, unsigned short& b0, unsigned short& b1)
{
  b0 = brn(x);
  float x1 = x - __uint_as_float((u32)b0 << 16);
  b1 = brn(x1);
}

// 3-term bf16 split: x ~= b0 + b1 + b2 (Sterbenz-exact residuals).
__device__ __forceinline__ void bsplit3(float x, unsigned short& b0, unsigned short& b1, unsigned short& b2)
{
  b0 = brn(x);
  float x1 = x - __uint_as_float((u32)b0 << 16);
  b1 = brn(x1);
  float x2 = x1 - __uint_as_float((u32)b1 << 16);
  b2 = brn(x2);
}

// ---------------------------------------------------------------------------
// Kernel 0: input dtype detection (bf16 vs fp32 bit patterns in w_qk).
// ---------------------------------------------------------------------------
__global__ __launch_bounds__(256) void k_detect(const u32* __restrict__ w, int* __restrict__ flag)
{
  int i = blockIdx.x * 256 + threadIdx.x;   // grid 512 -> 131072 u32
  float lo = bflo(w[i]);
  bool bad = !(fabsf(lo) <= 1024.0f);       // true also for NaN
  if (__any(bad)) {
    if ((threadIdx.x & 63) == 0) atomicOr(flag, 1);
  }
}

// ---------------------------------------------------------------------------
// Kernel P: prep weights. Transpose W[k][n] -> Wt[n][k], 3-term bf16 split
// for fp32 inputs. wt*: [2][512][512] u16 (plane 0 = wqk, 1 = wv).
// ---------------------------------------------------------------------------
__global__ __launch_bounds__(256) void k_prep(
    const u32* __restrict__ wqk, const u32* __restrict__ wv,
    const int* __restrict__ flag,
    unsigned short* __restrict__ wt0, unsigned short* __restrict__ wt1,
    unsigned short* __restrict__ wt2)
{
  const int which = blockIdx.y;
  const u32* W = which ? wv : wqk;
  const int tk = blockIdx.x >> 4, tn = blockIdx.x & 15;
  const int t = threadIdx.x;
  const int is32 = flag[0];
  __shared__ unsigned short h0s[32][36];
  __shared__ unsigned short h1s[32][36];
  __shared__ unsigned short h2s[32][36];
  if (is32) {
    const float* Wf = (const float*)W;
    #pragma unroll
    for (int it = 0; it < 4; ++it) {
      int idx = t + it * 256;           // 1024 = 32 k x 32 n
      int kk = idx >> 5, nn = idx & 31;
      float x = Wf[(size_t)(tk * 32 + kk) * 512 + tn * 32 + nn];
      bsplit3(x, h0s[kk][nn], h1s[kk][nn], h2s[kk][nn]);
    }
  } else {
    #pragma unroll
    for (int it = 0; it < 2; ++it) {
      int idx = t + it * 256;           // 512 u32 = 32 k x 16 pairs
      int kk = idx >> 4, np = idx & 15;
      u32 uv = W[(size_t)(tk * 32 + kk) * 256 + tn * 16 + np];
      h0s[kk][2 * np]     = (unsigned short)(uv & 0xffffu);
      h0s[kk][2 * np + 1] = (unsigned short)(uv >> 16);
      h1s[kk][2 * np] = 0; h1s[kk][2 * np + 1] = 0;
      h2s[kk][2 * np] = 0; h2s[kk][2 * np + 1] = 0;
    }
  }
  __syncthreads();
  size_t obase = ((size_t)which * 512 + tn * 32) * 512 + tk * 32;
  #pragma unroll
  for (int it = 0; it < 4; ++it) {
    int idx = t + it * 256;
    int nn = idx >> 5, kk = idx & 31;
    wt0[obase + (size_t)nn * 512 + kk] = h0s[kk][nn];
    wt1[obase + (size_t)nn * 512 + kk] = h1s[kk][nn];
    wt2[obase + (size_t)nn * 512 + kk] = h2s[kk][nn];
  }
}

// ---------------------------------------------------------------------------
// Kernel 1a: SCALAR projections for q and k (hash-feeding).
// Accumulation bit-identical to the R0-R2/R7-R12-proven kernel (same data,
// same LDS slots, same per-output k=0..511 fp32 fmac order). NEW: T14-style
// register prefetch — tile k+1 global loads issue BEFORE tile-k compute, so
// HBM/L2 latency hides under the ~1000-cyc FMA phase instead of stalling
// every wave at the staging barrier.
// ---------------------------------------------------------------------------
__global__ __launch_bounds__(256) void k_proj_s(
    const u32* __restrict__ dec, const u32* __restrict__ hid,
    const u32* __restrict__ wqk, const u32* __restrict__ wv,
    const int* __restrict__ flag,
    float* __restrict__ qb, float* __restrict__ kraw, float* __restrict__ vb)
{
  const int which = blockIdx.z;
  const u32* A = (which == 0) ? dec : hid;
  const u32* W = (which == 2) ? wv : wqk;
  const int m0 = blockIdx.x * 64;
  const int h  = blockIdx.y;
  const int t  = threadIdx.x;
  const int ty = t >> 4, tx = t & 15;
  const int is32 = flag[0];

  __shared__ __align__(16) float AsT[32][68];  // [kk][row i]; 272B stride
  __shared__ __align__(16) float Wst[32][64];  // [kk][col c]

  float acc[4][4];
  #pragma unroll
  for (int r = 0; r < 4; ++r)
    #pragma unroll
    for (int c = 0; c < 4; ++c) acc[r][c] = 0.0f;

  // prefetch registers (tile in flight)
  float pA[8], pW[8];
  u32 pAu[4], pWu[4];

  // ---- load tile 0 into regs
  if (is32) {
    const float* Af = (const float*)A;
    const float* Wf = (const float*)W;
    #pragma unroll
    for (int it = 0; it < 8; ++it) {
      int idx = t + it * 256;
      int i = idx >> 5, kk = idx & 31;
      pA[it] = Af[(size_t)(m0 + i) * HIDK + kk];
    }
    #pragma unroll
    for (int it = 0; it < 8; ++it) {
      int idx = t + it * 256;
      int kk = idx >> 6, cc = idx & 63;
      pW[it] = Wf[(size_t)kk * HIDK + h * 64 + cc];
    }
  } else {
    #pragma unroll
    for (int it = 0; it < 4; ++it) {
      int idx = t + it * 256;
      int i = idx >> 4, kp = idx & 15;
      pAu[it] = A[(size_t)(m0 + i) * (HIDK / 2) + kp];
    }
    #pragma unroll
    for (int it = 0; it < 4; ++it) {
      int idx = t + it * 256;
      int kk = idx >> 5, cp = idx & 31;
      pWu[it] = W[(size_t)kk * (HIDK / 2) + h * 32 + cp];
    }
  }

  for (int k0 = 0; k0 < HIDK; k0 += 32) {
    // ---- write the in-flight tile (regs -> LDS); vmcnt waits happen here
    if (is32) {
      #pragma unroll
      for (int it = 0; it < 8; ++it) {
        int idx = t + it * 256;
        int i = idx >> 5, kk = idx & 31;
        AsT[kk][i] = pA[it];
      }
      #pragma unroll
      for (int it = 0; it < 8; ++it) {
        int idx = t + it * 256;
        int kk = idx >> 6, cc = idx & 63;
        Wst[kk][cc] = pW[it];
      }
    } else {
      #pragma unroll
      for (int it = 0; it < 4; ++it) {
        int idx = t + it * 256;
        int i = idx >> 4, kp = idx & 15;
        u32 uv = pAu[it];
        AsT[2 * kp][i]     = bflo(uv);
        AsT[2 * kp + 1][i] = bfhi(uv);
      }
      #pragma unroll
      for (int it = 0; it < 4; ++it) {
        int idx = t + it * 256;
        int kk = idx >> 5, cp = idx & 31;
        u32 uv = pWu[it];
        Wst[kk][2 * cp]     = bflo(uv);
        Wst[kk][2 * cp + 1] = bfhi(uv);
      }
    }
    __syncthreads();

    // ---- issue next-tile global loads (latency hides under compute below)
    const int kn = k0 + 32;
    if (kn < HIDK) {
      if (is32) {
        const float* Af = (const float*)A;
        const float* Wf = (const float*)W;
        #pragma unroll
        for (int it = 0; it < 8; ++it) {
          int idx = t + it * 256;
          int i = idx >> 5, kk = idx & 31;
          pA[it] = Af[(size_t)(m0 + i) * HIDK + kn + kk];
        }
        #pragma unroll
        for (int it = 0; it < 8; ++it) {
          int idx = t + it * 256;
          int kk = idx >> 6, cc = idx & 63;
          pW[it] = Wf[(size_t)(kn + kk) * HIDK + h * 64 + cc];
        }
      } else {
        #pragma unroll
        for (int it = 0; it < 4; ++it) {
          int idx = t + it * 256;
          int i = idx >> 4, kp = idx & 15;
          pAu[it] = A[(size_t)(m0 + i) * (HIDK / 2) + (kn >> 1) + kp];
        }
        #pragma unroll
        for (int it = 0; it < 4; ++it) {
          int idx = t + it * 256;
          int kk = idx >> 5, cp = idx & 31;
          pWu[it] = W[(size_t)(kn + kk) * (HIDK / 2) + h * 32 + cp];
        }
      }
    }

    // ---- compute tile k0 from LDS (bit-identical chain)
    for (int kk = 0; kk < 32; ++kk) {
      float4 a4 = *reinterpret_cast<const float4*>(&AsT[kk][ty * 4]);  // rows ty*4..+3
      float4 w4 = *reinterpret_cast<const float4*>(&Wst[kk][tx * 4]);  // cols tx*4..+3
      acc[0][0] += a4.x * w4.x; acc[0][1] += a4.x * w4.y; acc[0][2] += a4.x * w4.z; acc[0][3] += a4.x * w4.w;
      acc[1][0] += a4.y * w4.x; acc[1][1] += a4.y * w4.y; acc[1][2] += a4.y * w4.z; acc[1][3] += a4.y * w4.w;
      acc[2][0] += a4.z * w4.x; acc[2][1] += a4.z * w4.y; acc[2][2] += a4.z * w4.z; acc[2][3] += a4.z * w4.w;
      acc[3][0] += a4.w * w4.x; acc[3][1] += a4.w * w4.y; acc[3][2] += a4.w * w4.z; acc[3][3] += a4.w * w4.w;
    }
    __syncthreads();
  }

  float* outp = (which == 0) ? qb : ((which == 1) ? kraw : vb);
  #pragma unroll
  for (int r = 0; r < 4; ++r) {
    int m = m0 + ty * 4 + r;
    int b = m >> 12, s = m & 4095;
    float4 o;
    o.x = acc[r][0]; o.y = acc[r][1]; o.z = acc[r][2]; o.w = acc[r][3];
    *reinterpret_cast<float4*>(outp + ((size_t)((b * HH + h) * SS + s)) * DD + tx * 4) = o;
  }
}

// ---------------------------------------------------------------------------
// Kernel 1b: MFMA projection for V ONLY (v = hid @ wv). R7-proven.
// ---------------------------------------------------------------------------
__global__ __launch_bounds__(256) void k_proj_v(
    const u32* __restrict__ hid,
    const unsigned short* __restrict__ wt0, const unsigned short* __restrict__ wt1,
    const unsigned short* __restrict__ wt2,
    const int* __restrict__ flag,
    float* __restrict__ vb)
{
  const int bid = blockIdx.x;              // grid 1024 = 8 x 128
  const int x = bid & 7, l = bid >> 3;     // l in [0,128)
  const int h = l & 7;
  const int m0 = (x * 16 + ((l >> 3) & 15)) * 64;
  const int t = threadIdx.x;
  const int w = t >> 6;
  const int r = t & 15, g = (t & 63) >> 4;
  const int is32 = flag[0];

  const u32* A = hid;
  const size_t wbase = (size_t)1 * 512 * 512 + (size_t)h * 64 * 512;  // wv plane
  const unsigned short* W0 = wt0 + wbase;
  const unsigned short* W1 = wt1 + wbase;
  const unsigned short* W2 = wt2 + wbase;

  __shared__ __align__(16) unsigned short A0[64][40];  // stride 80B
  __shared__ __align__(16) unsigned short A1[64][40];
  __shared__ __align__(16) unsigned short A2[64][40];
  __shared__ __align__(16) unsigned short B0[64][40];
  __shared__ __align__(16) unsigned short B1[64][40];
  __shared__ __align__(16) unsigned short B2[64][40];

  f32x4 acc[4];
  #pragma unroll
  for (int tn = 0; tn < 4; ++tn) { acc[tn][0] = 0.f; acc[tn][1] = 0.f; acc[tn][2] = 0.f; acc[tn][3] = 0.f; }

  for (int k0 = 0; k0 < HIDK; k0 += 32) {
    {
      const int n = t >> 2, kq = t & 3;
      *reinterpret_cast<uint4*>(&B0[n][kq * 8]) =
          *reinterpret_cast<const uint4*>(W0 + (size_t)n * 512 + k0 + kq * 8);
      if (is32) {
        *reinterpret_cast<uint4*>(&B1[n][kq * 8]) =
            *reinterpret_cast<const uint4*>(W1 + (size_t)n * 512 + k0 + kq * 8);
        *reinterpret_cast<uint4*>(&B2[n][kq * 8]) =
            *reinterpret_cast<const uint4*>(W2 + (size_t)n * 512 + k0 + kq * 8);
      }
    }
    if (is32) {
      const float* Af = (const float*)A;
      #pragma unroll
      for (int it = 0; it < 2; ++it) {
        int idx = t + it * 256;
        int m = idx >> 3, kq = idx & 7;
        float4 a4 = *reinterpret_cast<const float4*>(Af + (size_t)(m0 + m) * HIDK + k0 + kq * 4);
        ushort4 p0, p1, p2;
        bsplit3(a4.x, p0.x, p1.x, p2.x);
        bsplit3(a4.y, p0.y, p1.y, p2.y);
        bsplit3(a4.z, p0.z, p1.z, p2.z);
        bsplit3(a4.w, p0.w, p1.w, p2.w);
        *reinterpret_cast<ushort4*>(&A0[m][kq * 4]) = p0;
        *reinterpret_cast<ushort4*>(&A1[m][kq * 4]) = p1;
        *reinterpret_cast<ushort4*>(&A2[m][kq * 4]) = p2;
      }
    } else {
      #pragma unroll
      for (int it = 0; it < 2; ++it) {
        int idx = t + it * 256;
        int m = idx >> 3, kq = idx & 7;
        uint2 uv = *reinterpret_cast<const uint2*>(A + (size_t)(m0 + m) * (HIDK / 2) + (k0 >> 1) + kq * 2);
        *reinterpret_cast<uint2*>(&A0[m][kq * 4]) = uv;
      }
    }
    __syncthreads();

    bf16x8 a0 = *reinterpret_cast<const bf16x8*>(&A0[w * 16 + r][g * 8]);
    if (is32) {
      bf16x8 a1 = *reinterpret_cast<const bf16x8*>(&A1[w * 16 + r][g * 8]);
      bf16x8 a2 = *reinterpret_cast<const bf16x8*>(&A2[w * 16 + r][g * 8]);
      #pragma unroll
      for (int tn = 0; tn < 4; ++tn) {
        bf16x8 b0 = *reinterpret_cast<const bf16x8*>(&B0[tn * 16 + r][g * 8]);
        bf16x8 b1 = *reinterpret_cast<const bf16x8*>(&B1[tn * 16 + r][g * 8]);
        bf16x8 b2 = *reinterpret_cast<const bf16x8*>(&B2[tn * 16 + r][g * 8]);
        acc[tn] = __builtin_amdgcn_mfma_f32_16x16x32_bf16(a0, b0, acc[tn], 0, 0, 0);
        acc[tn] = __builtin_amdgcn_mfma_f32_16x16x32_bf16(a0, b1, acc[tn], 0, 0, 0);
        acc[tn] = __builtin_amdgcn_mfma_f32_16x16x32_bf16(a1, b0, acc[tn], 0, 0, 0);
        acc[tn] = __builtin_amdgcn_mfma_f32_16x16x32_bf16(a0, b2, acc[tn], 0, 0, 0);
        acc[tn] = __builtin_amdgcn_mfma_f32_16x16x32_bf16(a2, b0, acc[tn], 0, 0, 0);
        acc[tn] = __builtin_amdgcn_mfma_f32_16x16x32_bf16(a1, b1, acc[tn], 0, 0, 0);
      }
    } else {
      #pragma unroll
      for (int tn = 0; tn < 4; ++tn) {
        bf16x8 b0 = *reinterpret_cast<const bf16x8*>(&B0[tn * 16 + r][g * 8]);
        acc[tn] = __builtin_amdgcn_mfma_f32_16x16x32_bf16(a0, b0, acc[tn], 0, 0, 0);
      }
    }
    __syncthreads();
  }

  #pragma unroll
  for (int tn = 0; tn < 4; ++tn)
    #pragma unroll
    for (int rg = 0; rg < 4; ++rg) {
      int m = m0 + w * 16 + g * 4 + rg;
      int b = m >> 12, s = m & 4095;
      vb[((size_t)((b * HH + h) * SS + s)) * DD + tn * 16 + r] = acc[tn][rg];
    }
}

// ---------------------------------------------------------------------------
// Kernel 2: LSH hash. rotS [64][64], float4 LDS reads; grid z=16, one row
// per thread (R12-proven numerics + occupancy).
// ---------------------------------------------------------------------------
__global__ __launch_bounds__(256) void k_hash(
    const float* __restrict__ qb, const float* __restrict__ kraw,
    const u32* __restrict__ rots, const int* __restrict__ flag,
    u8* __restrict__ bucketOut)
{
  const int bhn = blockIdx.x;       // 0..63 : (b*8+h)*4+n
  const int which = blockIdx.y;     // 0=q 1=k
  const int sslice = blockIdx.z;    // 0..15
  const int t = threadIdx.x;
  const int bh = bhn >> 2;
  const int h  = bh & 7;
  const int n  = bhn & 3;
  const int is32 = flag[0];

  __shared__ __align__(16) float rotS[64][64];   // [d][r], 16 KB
  if (is32) {
    const float* rf = (const float*)rots;
    #pragma unroll
    for (int it = 0; it < 16; ++it) {
      int idx = t + it * 256;       // 4096 floats
      int d = idx >> 6, r = idx & 63;
      rotS[d][r] = rf[((size_t)((h * 64 + d) * 4 + n)) * 64 + r];
    }
  } else {
    #pragma unroll
    for (int it = 0; it < 8; ++it) {
      int idx = t + it * 256;       // 2048 u32 (4096 bf16)
      int d = idx >> 5, rp = idx & 31;
      u32 uv = rots[((size_t)((h * 64 + d) * 4 + n)) * 32 + rp];
      rotS[d][2 * rp]     = bflo(uv);
      rotS[d][2 * rp + 1] = bfhi(uv);
    }
  }
  __syncthreads();

  const float* src = ((which == 0) ? qb : kraw) + (size_t)bh * SS * DD;
  u8* bout = bucketOut + ((size_t)(which * 64 + bhn)) * SS;

  {
    int s = sslice * 256 + t;
    const float* row = src + (size_t)s * DD;
    float vec[64];
    #pragma unroll
    for (int d4 = 0; d4 < 16; ++d4) {
      float4 v4 = *reinterpret_cast<const float4*>(row + d4 * 4);
      vec[d4 * 4 + 0] = v4.x; vec[d4 * 4 + 1] = v4.y;
      vec[d4 * 4 + 2] = v4.z; vec[d4 * 4 + 3] = v4.w;
    }
    float bestP = -1e30f, bestN = -1e30f;
    int idxP = 0, idxN = 0;
    #pragma unroll 1
    for (int r0 = 0; r0 < 64; r0 += 16) {
      float acc[16];
      #pragma unroll
      for (int rr = 0; rr < 16; ++rr) acc[rr] = 0.0f;
      #pragma unroll
      for (int d = 0; d < 64; ++d) {
        float vd = vec[d];
        #pragma unroll
        for (int q4 = 0; q4 < 4; ++q4) {
          float4 rv4 = *reinterpret_cast<const float4*>(&rotS[d][r0 + q4 * 4]);
          acc[q4 * 4 + 0] += vd * rv4.x;
          acc[q4 * 4 + 1] += vd * rv4.y;
          acc[q4 * 4 + 2] += vd * rv4.z;
          acc[q4 * 4 + 3] += vd * rv4.w;
        }
      }
      #pragma unroll
      for (int rr = 0; rr < 16; ++rr) {
        float a = acc[rr];
        int r = r0 + rr;
        if (a > bestP) { bestP = a; idxP = r; }
        if (-a > bestN) { bestN = -a; idxN = r; }
      }
    }
    int bucket = (bestP >= bestN) ? idxP : (64 + idxN);
    bout[s] = (u8)bucket;
  }
}

// ---------------------------------------------------------------------------
// Kernel 3: PARALLEL stable counting sort per (b,h,round,which).
// ---------------------------------------------------------------------------
__global__ __launch_bounds__(256) void k_sort(
    const u8* __restrict__ bucketIn, int* __restrict__ sq_pos,
    int* __restrict__ sk_pos, int* __restrict__ sk_rank)
{
  const int bhn = blockIdx.x, which = blockIdx.y;
  const int t = threadIdx.x;
  const int bh = bhn >> 2, n = bhn & 3;
  const int lane = t & 63, w = t >> 6;

  __shared__ u8 bk[4096];
  __shared__ u8 rk[4096];
  __shared__ int chunkh[64 * 128];   // [chunk][bin], 32 KB
  __shared__ int hist[128];
  __shared__ int scanS[128];

  const u8* bin = bucketIn + ((size_t)(which * 64 + bhn)) * SS;
  #pragma unroll
  for (int it = 0; it < 4; ++it)
    ((u32*)bk)[t + it * 256] = ((const u32*)bin)[t + it * 256];
  #pragma unroll
  for (int it = 0; it < 32; ++it) chunkh[t + it * 256] = 0;
  if (t < 128) hist[t] = 0;
  __syncthreads();

  const unsigned long long below = (lane == 0) ? 0ull : (~0ull >> (64 - lane));
  #pragma unroll 1
  for (int k = 0; k < 16; ++k) {
    const int c = w * 16 + k;
    const int s = c * 64 + lane;
    const int b = bk[s];
    unsigned long long m = ~0ull;
    #pragma unroll
    for (int bit = 0; bit < 7; ++bit) {
      unsigned long long vote = __ballot((b >> bit) & 1);
      m &= ((b >> bit) & 1) ? vote : ~vote;
    }
    const int r = (int)__popcll(m & below);
    rk[s] = (u8)r;
    if (r == 0) {
      const int cnt = (int)__popcll(m);
      chunkh[c * 128 + b] = cnt;
      atomicAdd(&hist[b], cnt);
    }
  }
  __syncthreads();

  if (t < 128) scanS[t] = hist[t];
  __syncthreads();
  for (int off = 1; off < 128; off <<= 1) {
    int add = 0;
    if (t < 128 && t >= off) add = scanS[t - off];
    __syncthreads();
    if (t < 128) scanS[t] += add;
    __syncthreads();
  }
  if (t < 128) {
    int run = scanS[t] - hist[t];    // global bin start
    #pragma unroll 1
    for (int c = 0; c < 64; ++c) {
      int v = chunkh[c * 128 + t];
      chunkh[c * 128 + t] = run;
      run += v;
    }
  }
  __syncthreads();

  int* outp = ((which == 0) ? sq_pos : sk_pos) + (size_t)bh * RANKS + n * SS;
  int* rnkp = sk_rank + (size_t)bh * RANKS + n * SS;
  #pragma unroll 1
  for (int k = 0; k < 16; ++k) {
    const int c = w * 16 + k;
    const int s = c * 64 + lane;
    const int b = bk[s];
    const int pos = chunkh[c * 128 + b] + (int)rk[s];
    outp[pos] = s;
    if (which) rnkp[s] = pos;
  }
}

// ---------------------------------------------------------------------------
// Kernel 4: single attention pass, BOTH matmuls on MFMA (R11-proven).
//   QK: 2-term bf16 split of Q and normalized K, 3 MFMAs.
//   PV: P = exp(dots) 2-term split x V 2-term split, 3 MFMAs; den exact fp32.
// LDS overlay (byte offsets):
//   phase A: Qh@0 Ql@9216 [64][72]u16, Kh@18432 Kl@36864 [128][72]u16 (55.3KB)
//   phase B: Ph@0 Pl@17408 [64][136]u16, Vth@34816 Vtl@52224 [64][136]u16 (69.6KB)
// C/D layouts use the HW-verified col=lane&15, row=(lane>>4)*4+reg mapping.
// ---------------------------------------------------------------------------
__global__ __launch_bounds__(256) void k_attn(
    const float* __restrict__ qb, const float* __restrict__ kraw,
    const float* __restrict__ vb,
    const int* __restrict__ sq_pos, const int* __restrict__ sk_pos,
    const int mode,
    float* __restrict__ outA, float* __restrict__ denA,
    float* __restrict__ numB, float* __restrict__ denB)
{
  const int c = blockIdx.x;
  const int h = blockIdx.y, b = blockIdx.z;
  const int bh = b * HH + h;
  const int t = threadIdx.x;
  const int cprev = (c + NCC - 1) & (NCC - 1);

  __shared__ __align__(16) char smem[69632];
  __shared__ int kposS[128], mposS[128];

  unsigned short* Qh = (unsigned short*)smem;            // [64][72]
  unsigned short* Ql = (unsigned short*)(smem + 9216);   // [64][72]
  unsigned short* Kh = (unsigned short*)(smem + 18432);  // [128][72]
  unsigned short* Kl = (unsigned short*)(smem + 36864);  // [128][72]
  unsigned short* Ph  = (unsigned short*)smem;           // [64][136]
  unsigned short* Pl  = (unsigned short*)(smem + 17408); // [64][136]
  unsigned short* Vth = (unsigned short*)(smem + 34816); // [64][136]
  unsigned short* Vtl = (unsigned short*)(smem + 52224); // [64][136]

  if (t < 128) {
    int slot = (t < 64) ? (cprev * 64 + t) : (c * 64 + (t - 64));
    kposS[t] = sk_pos[(size_t)bh * RANKS + slot];
    mposS[t] = sq_pos[(size_t)bh * RANKS + slot];
  }
  __syncthreads();

  const float* qbase = qb + (size_t)bh * SS * DD;
  const float* kbase = kraw + (size_t)bh * SS * DD;
  const float* vbase = vb + (size_t)bh * SS * DD;

  // stage Q: gather rows, 2-term split
  #pragma unroll
  for (int it = 0; it < 4; ++it) {
    int idx = t + it * 256;
    int i = idx >> 4, d4 = idx & 15;
    float4 q4 = *reinterpret_cast<const float4*>(qbase + (size_t)mposS[64 + i] * DD + d4 * 4);
    ushort4 hh, ll;
    bsplit2(q4.x, hh.x, ll.x); bsplit2(q4.y, hh.y, ll.y);
    bsplit2(q4.z, hh.z, ll.z); bsplit2(q4.w, hh.w, ll.w);
    *reinterpret_cast<ushort4*>(Qh + (size_t)i * 72 + d4 * 4) = hh;
    *reinterpret_cast<ushort4*>(Ql + (size_t)i * 72 + d4 * 4) = ll;
  }
  // stage K: gather rows, normalize (16-lane shuffle row-sumsq), 2-term split
  #pragma unroll
  for (int it = 0; it < 8; ++it) {
    int idx = t + it * 256;
    int j = idx >> 4, d4 = idx & 15;
    float4 k4 = *reinterpret_cast<const float4*>(kbase + (size_t)kposS[j] * DD + d4 * 4);
    float ss = k4.x * k4.x + k4.y * k4.y + k4.z * k4.z + k4.w * k4.w;
    ss += __shfl_xor(ss, 1); ss += __shfl_xor(ss, 2);
    ss += __shfl_xor(ss, 4); ss += __shfl_xor(ss, 8);
    float scj = 0.125f / sqrtf(ss * (1.0f / 64.0f) + 1e-6f);
    k4.x *= scj; k4.y *= scj; k4.z *= scj; k4.w *= scj;
    ushort4 hh, ll;
    bsplit2(k4.x, hh.x, ll.x); bsplit2(k4.y, hh.y, ll.y);
    bsplit2(k4.z, hh.z, ll.z); bsplit2(k4.w, hh.w, ll.w);
    *reinterpret_cast<ushort4*>(Kh + (size_t)j * 72 + d4 * 4) = hh;
    *reinterpret_cast<ushort4*>(Kl + (size_t)j * 72 + d4 * 4) = ll;
  }
  __syncthreads();

  // QK^T via MFMA (R10-proven): dots[w*16+g*4+reg][kt*16+r]
  const int w = t >> 6, r = t & 15, g = (t & 63) >> 4;
  f32x4 dacc[8];
  #pragma unroll
  for (int kt = 0; kt < 8; ++kt) {
    f32x4 a; a[0] = 0.f; a[1] = 0.f; a[2] = 0.f; a[3] = 0.f;
    #pragma unroll
    for (int ks = 0; ks < 2; ++ks) {
      const int qo = (w * 16 + r) * 72 + ks * 32 + g * 8;
      const int ko = (kt * 16 + r) * 72 + ks * 32 + g * 8;
      bf16x8 qh_ = *reinterpret_cast<const bf16x8*>(Qh + qo);
      bf16x8 ql_ = *reinterpret_cast<const bf16x8*>(Ql + qo);
      bf16x8 kh_ = *reinterpret_cast<const bf16x8*>(Kh + ko);
      bf16x8 kl_ = *reinterpret_cast<const bf16x8*>(Kl + ko);
      a = __builtin_amdgcn_mfma_f32_16x16x32_bf16(qh_, kh_, a, 0, 0, 0);
      a = __builtin_amdgcn_mfma_f32_16x16x32_bf16(qh_, kl_, a, 0, 0, 0);
      a = __builtin_amdgcn_mfma_f32_16x16x32_bf16(ql_, kh_, a, 0, 0, 0);
    }
    dacc[kt] = a;
  }
  __syncthreads();  // all frag reads done; phase-B buffers may overwrite

  // issue V gather early (j = idx&127 row, d4 = idx>>7 16B-chunk)
  float4 vld[8];
  #pragma unroll
  for (int it = 0; it < 8; ++it) {
    int idx = t + it * 256;
    int j = idx & 127, d4 = idx >> 7;
    vld[it] = *reinterpret_cast<const float4*>(vbase + (size_t)kposS[j] * DD + d4 * 4);
  }

  // mask + exp + den in registers (rows w*16+g*4+rg, cols kt*16+r)
  int qp0 = mposS[64 + w * 16 + g * 4 + 0];
  int qp1 = mposS[64 + w * 16 + g * 4 + 1];
  int qp2 = mposS[64 + w * 16 + g * 4 + 2];
  int qp3 = mposS[64 + w * 16 + g * 4 + 3];
  float ex[8][4];
  float rs0 = 0.f, rs1 = 0.f, rs2 = 0.f, rs3 = 0.f;
  #pragma unroll
  for (int kt = 0; kt < 8; ++kt) {
    int cp = mposS[kt * 16 + r];
    float d0 = (cp == qp0) ? -100000.0f : dacc[kt][0];
    float d1 = (cp == qp1) ? -100000.0f : dacc[kt][1];
    float d2 = (cp == qp2) ? -100000.0f : dacc[kt][2];
    float d3 = (cp == qp3) ? -100000.0f : dacc[kt][3];
    float e0 = expf(d0), e1 = expf(d1), e2 = expf(d2), e3 = expf(d3);
    ex[kt][0] = e0; ex[kt][1] = e1; ex[kt][2] = e2; ex[kt][3] = e3;
    rs0 += e0; rs1 += e1; rs2 += e2; rs3 += e3;
  }
  #pragma unroll
  for (int st = 1; st <= 8; st <<= 1) {
    rs0 += __shfl_xor(rs0, st); rs1 += __shfl_xor(rs1, st);
    rs2 += __shfl_xor(rs2, st); rs3 += __shfl_xor(rs3, st);
  }
  const int n = c >> 6;
  if (r == 0) {
    #pragma unroll
    for (int rg = 0; rg < 4; ++rg) {
      float rsv = (rg == 0) ? rs0 : (rg == 1) ? rs1 : (rg == 2) ? rs2 : rs3;
      int q = w * 16 + g * 4 + rg;
      if (mode) denB[(size_t)(bh * NHH + n) * SS + (c & 63) * 64 + q] = rsv;
      else      atomicAdd(&denA[(size_t)bh * SS + kposS[64 + q]], rsv);
    }
  }

  // write P planes (2-term split of exp values)
  #pragma unroll
  for (int kt = 0; kt < 8; ++kt)
    #pragma unroll
    for (int rg = 0; rg < 4; ++rg) {
      unsigned short hi, lo;
      bsplit2(ex[kt][rg], hi, lo);
      size_t po = (size_t)(w * 16 + g * 4 + rg) * 136 + kt * 16 + r;
      Ph[po] = hi;
      Pl[po] = lo;
    }
  // write V^T planes (2-term split); per (d,j): 2-way bank access (free)
  #pragma unroll
  for (int it = 0; it < 8; ++it) {
    int idx = t + it * 256;
    int j = idx & 127, d4 = idx >> 7;
    float4 v4 = vld[it];
    unsigned short h0, l0, h1, l1, h2, l2, h3, l3;
    bsplit2(v4.x, h0, l0); bsplit2(v4.y, h1, l1);
    bsplit2(v4.z, h2, l2); bsplit2(v4.w, h3, l3);
    Vth[(size_t)(d4 * 4 + 0) * 136 + j] = h0; Vtl[(size_t)(d4 * 4 + 0) * 136 + j] = l0;
    Vth[(size_t)(d4 * 4 + 1) * 136 + j] = h1; Vtl[(size_t)(d4 * 4 + 1) * 136 + j] = l1;
    Vth[(size_t)(d4 * 4 + 2) * 136 + j] = h2; Vtl[(size_t)(d4 * 4 + 2) * 136 + j] = l2;
    Vth[(size_t)(d4 * 4 + 3) * 136 + j] = h3; Vtl[(size_t)(d4 * 4 + 3) * 136 + j] = l3;
  }
  __syncthreads();

  // PV via MFMA: O[w*16+g*4+reg][tn*16+r] = sum_k P[q][k] V[k][d]
  #pragma unroll
  for (int tn = 0; tn < 4; ++tn) {
    f32x4 a; a[0] = 0.f; a[1] = 0.f; a[2] = 0.f; a[3] = 0.f;
    #pragma unroll
    for (int ks = 0; ks < 4; ++ks) {
      const int po = (w * 16 + r) * 136 + ks * 32 + g * 8;
      const int vo = (tn * 16 + r) * 136 + ks * 32 + g * 8;
      bf16x8 ph_ = *reinterpret_cast<const bf16x8*>(Ph + po);
      bf16x8 pl_ = *reinterpret_cast<const bf16x8*>(Pl + po);
      bf16x8 vh_ = *reinterpret_cast<const bf16x8*>(Vth + vo);
      bf16x8 vl_ = *reinterpret_cast<const bf16x8*>(Vtl + vo);
      a = __builtin_amdgcn_mfma_f32_16x16x32_bf16(ph_, vh_, a, 0, 0, 0);
      a = __builtin_amdgcn_mfma_f32_16x16x32_bf16(ph_, vl_, a, 0, 0, 0);
      a = __builtin_amdgcn_mfma_f32_16x16x32_bf16(pl_, vh_, a, 0, 0, 0);
    }
    // epilogue for this d-tile
    #pragma unroll
    for (int reg = 0; reg < 4; ++reg) {
      int q = w * 16 + g * 4 + reg;
      int d = tn * 16 + r;
      if (mode) {
        numB[((size_t)(bh * NHH + n) * SS + (c & 63) * 64 + q) * DD + d] = a[reg];
      } else {
        atomicAdd(&outA[((size_t)(b * SS + kposS[64 + q])) * (HH * DD) + h * DD + d], a[reg]);
      }
    }
  }
}

// ---------------------------------------------------------------------------
// Kernel 5 (big-ws path): gather-combine.
// ---------------------------------------------------------------------------
__global__ __launch_bounds__(256) void k_combine(
    const float* __restrict__ numB, const float* __restrict__ denB,
    const int* __restrict__ sk_rank, float* __restrict__ outp)
{
  const int bh = blockIdx.y;
  const int s = blockIdx.x * 16 + (threadIdx.x >> 4);
  const int lane = threadIdx.x & 15;
  const int b = bh >> 3, h = bh & 7;
  float4 acc = make_float4(0.f, 0.f, 0.f, 0.f);
  float den = 0.f;
  #pragma unroll
  for (int n = 0; n < NHH; ++n) {
    int r = sk_rank[(size_t)bh * RANKS + n * SS + s];
    size_t rowi = (size_t)(bh * NHH + n) * SS + r;
    float4 v = *reinterpret_cast<const float4*>(numB + rowi * DD + lane * 4);
    acc.x += v.x; acc.y += v.y; acc.z += v.z; acc.w += v.w;
    den += denB[rowi];
  }
  float inv = 1.0f / den;
  acc.x *= inv; acc.y *= inv; acc.z *= inv; acc.w *= inv;
  *reinterpret_cast<float4*>(outp + ((size_t)(b * SS + s)) * (HH * DD) + h * DD + lane * 4) = acc;
}

// ---------------------------------------------------------------------------
// Kernel 5' (fallback path): divide accumulated numerator by denominator.
// ---------------------------------------------------------------------------
__global__ __launch_bounds__(256) void k_div(
    const float* __restrict__ den, float* __restrict__ outp)
{
  int idx = blockIdx.x * 256 + threadIdx.x;  // grid 4096 -> 1,048,576 float4
  int f = idx * 4;
  int col = f & 511;
  int h = col >> 6;
  int srow = f >> 9;                          // b*4096+s
  int b = srow >> 12, s = srow & 4095;
  float inv = 1.0f / den[(size_t)(b * HH + h) * SS + s];
  float4 v = *reinterpret_cast<float4*>(outp + (size_t)f);
  v.x *= inv; v.y *= inv; v.z *= inv; v.w *= inv;
  *reinterpret_cast<float4*>(outp + (size_t)f) = v;
}

// ---------------------------------------------------------------------------
// Kernel Z: zero the fp32 output (fallback path; harness poisons d_out).
// ---------------------------------------------------------------------------
__global__ __launch_bounds__(256) void k_zero_out(float* __restrict__ outp)
{
  int flat = blockIdx.x * 256 + threadIdx.x;  // grid 4096 -> 1,048,576 float4
  float4 z = make_float4(0.f, 0.f, 0.f, 0.f);
  *reinterpret_cast<float4*>(outp + (size_t)flat * 4) = z;
}

// ---------------------------------------------------------------------------
extern "C" void kernel_launch(void* const* d_in, const int* in_sizes, int n_in,
                              void* d_out, int out_size, void* d_ws, size_t ws_size,
                              hipStream_t stream)
{
  (void)in_sizes; (void)n_in; (void)out_size;
  const u32* dec = (const u32*)d_in[0];
  const u32* hid = (const u32*)d_in[1];
  const u32* wqk = (const u32*)d_in[2];
  const u32* wv  = (const u32*)d_in[3];
  const u32* rot = (const u32*)d_in[4];

  const size_t QKV  = (size_t)BB * HH * SS * DD;   // 4,194,304 elems
  const size_t LOGU = (size_t)BB * HH * NHH * SS;  // 262,144

  float* qb      = (float*)d_ws;
  float* kraw    = qb + QKV;
  float* vb      = kraw + QKV;
  float* den     = vb + QKV;                  // LOGU floats
  int*   sq_pos  = (int*)(den + LOGU);
  int*   sk_pos  = sq_pos + LOGU;
  int*   sk_rank = sk_pos + LOGU;
  u8*    buckets = (u8*)(sk_rank + LOGU);
  int*   flag    = (int*)(buckets + (size_t)2 * 64 * SS);
  const size_t numb_off = 55050496;           // align_up(low region, 256)
  float* numb    = (float*)((char*)d_ws + numb_off);
  // wt planes live INSIDE the numb region (numb not yet live during proj):
  unsigned short* wt0 = (unsigned short*)numb;
  unsigned short* wt1 = wt0 + (size_t)2 * 512 * 512;
  unsigned short* wt2 = wt1 + (size_t)2 * 512 * 512;
  const size_t need_big = numb_off + (size_t)NHH * QKV * sizeof(float);  // 122,159,360
  const int big = (ws_size >= need_big) ? 1 : 0;

  hipMemsetAsync(flag, 0, sizeof(int), stream);
  k_detect<<<dim3(512), 256, 0, stream>>>(wqk, flag);
  k_prep<<<dim3(256, 2), 256, 0, stream>>>(wqk, wv, flag, wt0, wt1, wt2);
  // q,k: scalar (hash-feeding, bit-identical accumulation). v: MFMA (R7-proven).
  k_proj_s<<<dim3(128, 8, 2), 256, 0, stream>>>(dec, hid, wqk, wv, flag, qb, kraw, vb);
  k_proj_v<<<dim3(1024), 256, 0, stream>>>(hid, wt0, wt1, wt2, flag, vb);
  k_hash<<<dim3(64, 2, 16), 256, 0, stream>>>(qb, kraw, rot, flag, buckets);
  k_sort<<<dim3(64, 2), 256, 0, stream>>>(buckets, sq_pos, sk_pos, sk_rank);

  if (big) {
    k_attn<<<dim3(NCC, HH, BB), 256, 0, stream>>>(
        qb, kraw, vb, sq_pos, sk_pos, 1, nullptr, nullptr, numb, den);
    k_combine<<<dim3(SS / 16, BB * HH), 256, 0, stream>>>(
        numb, den, sk_rank, (float*)d_out);
  } else {
    hipMemsetAsync(den, 0, (size_t)BB * HH * SS * sizeof(float), stream);
    k_zero_out<<<dim3(4096), 256, 0, stream>>>((float*)d_out);
    k_attn<<<dim3(NCC, HH, BB), 256, 0, stream>>>(
        qb, kraw, vb, sq_pos, sk_pos, 0, (float*)d_out, den, nullptr, nullptr);
    k_div<<<dim3(4096), 256, 0, stream>>>(den, (float*)d_out);
  }
}